// Round 7
// baseline (496.406 us; speedup 1.0000x reference)
//
#include <hip/hip_runtime.h>
#include <hip/hip_bf16.h>
#include <hip/hip_fp16.h>

// GCN 3-layer forward for MI355X (gfx950).
//   1. histogram in-degree over dst          (atomicAdd int, x4 unrolled)
//   2. 3-kernel multi-block exclusive scan -> CSR rowptr (+fused dinv)
//   3. scatter edges into CSR (src only, nt-stores, x4 unrolled)
//   4. per layer: split-bf16 MFMA GEMM h=X@W (fp16 output), then
//      wave-per-node CSR gather-reduce, w = dinv[s]*dinv[n] on the fly.
// R2: agg edge loop unrolled (independent H-row gathers in flight).
// R3: scan parallelized; agg unroll 4 -> 8.
// R4: GEMM on matrix cores via split-bf16 (3 MFMAs, ~2^-17 rel err).
// R5: H stored fp16 (agg was BW-pinned); unroll back to 8; dinv fused.
// R6: int2-packed scatter + XCD grouping: write-amp stayed 64B/store,
//     grouping bought nothing (VALUBusy 6%, 1.85 TB/s -> latency-bound).
// R7: revert grouping; scatter stores src ONLY (4B, nontemporal, x4
//     unrolled single pass); agg computes w on the fly from dinv.

constexpr int N_NODES = 100000;
constexpr int E_EDGES = 1600000;
constexpr int SCAN_B = (N_NODES + 1023) / 1024;  // 98 blocks of 1024 elems

typedef short short8 __attribute__((ext_vector_type(8)));
typedef float f32x4 __attribute__((ext_vector_type(4)));
typedef int iv4 __attribute__((ext_vector_type(4)));

__global__ __launch_bounds__(256) void count_kernel(
    const int* __restrict__ dst, int* __restrict__ cnt) {
  int i = blockIdx.x * 256 + threadIdx.x;
  if (i >= E_EDGES / 4) return;
  iv4 d = __builtin_nontemporal_load((const iv4*)dst + i);
  atomicAdd(&cnt[d.x], 1);
  atomicAdd(&cnt[d.y], 1);
  atomicAdd(&cnt[d.z], 1);
  atomicAdd(&cnt[d.w], 1);
}

// --- 3-kernel scan: cnt[N] -> rowptr[N+1] (exclusive), dinv fused ---
__global__ __launch_bounds__(256) void scan_part_kernel(
    const int* __restrict__ cnt, int* __restrict__ bsum) {
  __shared__ int red[256];
  const int t = threadIdx.x;
  int base = blockIdx.x * 1024 + t * 4;
  int4 v = make_int4(0, 0, 0, 0);
  if (base < N_NODES) v = *(const int4*)(cnt + base);
  red[t] = v.x + v.y + v.z + v.w;
  __syncthreads();
  for (int off = 128; off > 0; off >>= 1) {
    if (t < off) red[t] += red[t + off];
    __syncthreads();
  }
  if (t == 0) bsum[blockIdx.x] = red[0];
}

__global__ __launch_bounds__(128) void scan_tops_kernel(
    const int* __restrict__ bsum, int* __restrict__ boff,
    int* __restrict__ rowptr) {
  __shared__ int part[128];
  const int t = threadIdx.x;
  int v = (t < SCAN_B) ? bsum[t] : 0;
  part[t] = v;
  __syncthreads();
  for (int off = 1; off < 128; off <<= 1) {
    int add = (t >= off) ? part[t - off] : 0;
    __syncthreads();
    part[t] += add;
    __syncthreads();
  }
  if (t < SCAN_B) boff[t] = part[t] - v;  // exclusive
  if (t == 127) rowptr[N_NODES] = part[127];
}

__global__ __launch_bounds__(256) void scan_write_kernel(
    const int* __restrict__ cnt, const int* __restrict__ boff,
    int* __restrict__ rowptr, float* __restrict__ dinv) {
  __shared__ int part[256];
  const int t = threadIdx.x;
  int base = blockIdx.x * 1024 + t * 4;
  int4 v = make_int4(0, 0, 0, 0);
  if (base < N_NODES) v = *(const int4*)(cnt + base);
  int s = v.x + v.y + v.z + v.w;
  part[t] = s;
  __syncthreads();
  for (int off = 1; off < 256; off <<= 1) {
    int add = (t >= off) ? part[t - off] : 0;
    __syncthreads();
    part[t] += add;
    __syncthreads();
  }
  if (base < N_NODES) {
    int run = boff[blockIdx.x] + part[t] - s;
    int4 o;
    o.x = run;
    o.y = run + v.x;
    o.z = run + v.x + v.y;
    o.w = run + v.x + v.y + v.z;
    *(int4*)(rowptr + base) = o;
    float4 dv;
    dv.x = rsqrtf((float)v.x + 1.0f);  // +1 self loop
    dv.y = rsqrtf((float)v.y + 1.0f);
    dv.z = rsqrtf((float)v.z + 1.0f);
    dv.w = rsqrtf((float)v.w + 1.0f);
    *(float4*)(dinv + base) = dv;
  }
}

// Scatter: one pass, 4 edges/thread via int4 loads, src-only payload,
// nontemporal 4B stores (no L2 line allocate for random scatter).
__global__ __launch_bounds__(256) void scatter_kernel(
    const int* __restrict__ src, const int* __restrict__ dst,
    const int* __restrict__ rowptr, int* __restrict__ cursor,
    int* __restrict__ eSrc) {
  int i = blockIdx.x * 256 + threadIdx.x;
  if (i >= E_EDGES / 4) return;
  iv4 d = __builtin_nontemporal_load((const iv4*)dst + i);
  iv4 s = __builtin_nontemporal_load((const iv4*)src + i);
  int p0 = rowptr[d.x] + atomicAdd(&cursor[d.x], 1);
  int p1 = rowptr[d.y] + atomicAdd(&cursor[d.y], 1);
  int p2 = rowptr[d.z] + atomicAdd(&cursor[d.z], 1);
  int p3 = rowptr[d.w] + atomicAdd(&cursor[d.w], 1);
  __builtin_nontemporal_store(s.x, eSrc + p0);
  __builtin_nontemporal_store(s.y, eSrc + p1);
  __builtin_nontemporal_store(s.z, eSrc + p2);
  __builtin_nontemporal_store(s.w, eSrc + p3);
}

// bf16 split helpers (manual RNE; inputs finite)
__device__ inline ushort bf_round(float x) {
  uint u = __float_as_uint(x);
  return (ushort)((u + 0x7FFFu + ((u >> 16) & 1u)) >> 16);
}
__device__ inline ushort bf_split(float x, float* rem) {
  ushort h = bf_round(x);
  *rem = x - __uint_as_float((uint)h << 16);
  return h;
}

// Pack W [128][OC] f32 into fragment-linear hi/lo bf16:
// chunk id = ((nt*4 + ks)*4 + g)*16 + col holds 8 bf16:
//   W[ks*32 + g*8 + j][nt*16 + col], j = 0..7.
template <int OC>
__global__ __launch_bounds__(256) void packw_kernel(
    const float* __restrict__ W, ushort* __restrict__ hi,
    ushort* __restrict__ lo) {
  int id = blockIdx.x * 256 + threadIdx.x;
  if (id >= OC * 16) return;  // (OC/16)*4*4*16 chunks
  int col = id & 15;
  int g = (id >> 4) & 3;
  int ks = (id >> 6) & 3;
  int nt = id >> 8;
  int k0 = ks * 32 + g * 8;
  int n = nt * 16 + col;
  ushort h8[8], l8[8];
#pragma unroll
  for (int j = 0; j < 8; ++j) {
    float rem;
    h8[j] = bf_split(W[(size_t)(k0 + j) * OC + n], &rem);
    l8[j] = bf_round(rem);
  }
  size_t base = (size_t)id * 8;
#pragma unroll
  for (int j = 0; j < 8; ++j) {
    hi[base + j] = h8[j];
    lo[base + j] = l8[j];
  }
}

// Split-bf16 MFMA GEMM: H[N, OC] = X[N, 128] @ W[128, OC], H in fp16.
// 4 waves/block, 16 rows/wave (M-tile 64). W (packed hi/lo) staged in LDS;
// A-fragments loaded direct from global (X is L2/L3-resident) and split
// to hi/lo in registers. 3 MFMAs per (nt, ks): hi*hi + hi*lo + lo*hi.
template <int OC>
__global__ __launch_bounds__(256) void gemm_kernel(
    const float* __restrict__ X, const ushort* __restrict__ Whi,
    const ushort* __restrict__ Wlo, __half* __restrict__ H) {
  constexpr int NT = OC / 16;
  __shared__ ushort sWhi[OC * 128];
  __shared__ ushort sWlo[OC * 128];
  const int t = threadIdx.x;
  {  // stage packed W (contiguous, coalesced uint4 copies)
    const uint4* gh = (const uint4*)Whi;
    const uint4* gl = (const uint4*)Wlo;
    uint4* sh = (uint4*)sWhi;
    uint4* sl = (uint4*)sWlo;
    for (int i = t; i < OC * 128 / 8; i += 256) {
      sh[i] = gh[i];
      sl[i] = gl[i];
    }
  }
  const int wid = t >> 6;
  const int lane = t & 63;
  const int row = blockIdx.x * 64 + wid * 16 + (lane & 15);
  const bool ok = row < N_NODES;
  const int g = lane >> 4;  // k-group 0..3

  // Load + split A fragments for all 4 k-steps
  short8 ahi[4], alo[4];
  const float* xr = X + (size_t)row * 128;
#pragma unroll
  for (int ks = 0; ks < 4; ++ks) {
    float f[8];
    if (ok) {
      float4 f0 = *(const float4*)(xr + ks * 32 + g * 8);
      float4 f1 = *(const float4*)(xr + ks * 32 + g * 8 + 4);
      f[0] = f0.x; f[1] = f0.y; f[2] = f0.z; f[3] = f0.w;
      f[4] = f1.x; f[5] = f1.y; f[6] = f1.z; f[7] = f1.w;
    } else {
#pragma unroll
      for (int j = 0; j < 8; ++j) f[j] = 0.f;
    }
    union { short8 v; ushort u[8]; } h, l;
#pragma unroll
    for (int j = 0; j < 8; ++j) {
      float rem;
      h.u[j] = bf_split(f[j], &rem);
      l.u[j] = bf_round(rem);
    }
    ahi[ks] = h.v;
    alo[ks] = l.v;
  }
  __syncthreads();

#pragma unroll
  for (int nt = 0; nt < NT; ++nt) {
    f32x4 acc = {0.f, 0.f, 0.f, 0.f};
#pragma unroll
    for (int ks = 0; ks < 4; ++ks) {
      int off = (((nt * 4 + ks) * 4 + g) * 16 + (lane & 15)) * 8;
      short8 bhi = *(const short8*)&sWhi[off];
      short8 blo = *(const short8*)&sWlo[off];
      acc = __builtin_amdgcn_mfma_f32_16x16x32_bf16(alo[ks], bhi, acc, 0, 0, 0);
      acc = __builtin_amdgcn_mfma_f32_16x16x32_bf16(ahi[ks], blo, acc, 0, 0, 0);
      acc = __builtin_amdgcn_mfma_f32_16x16x32_bf16(ahi[ks], bhi, acc, 0, 0, 0);
    }
    // C: col = lane&15, row_in_tile = (lane>>4)*4 + r
#pragma unroll
    for (int r = 0; r < 4; ++r) {
      int rr = blockIdx.x * 64 + wid * 16 + g * 4 + r;
      if (rr < N_NODES)
        H[(size_t)rr * OC + nt * 16 + (lane & 15)] = __float2half(acc[r]);
    }
  }
}

// Wave-per-node CSR aggregation over fp16 H, src-only edges:
// Y[n] = relu(b + dinv[n]^2*H[n] + sum_e dinv[s]*dinv[n] * H[s]), f32 out.
// Edge loop unrolled x8 (two int4 loads of 4 srcs); w computed on the fly
// (dinv[s] is a wave-uniform broadcast from the L2-resident 400KB table).
template <int OC>
__global__ __launch_bounds__(256) void agg_kernel(
    const __half* __restrict__ H, const int* __restrict__ rowptr,
    const int* __restrict__ eSrc, const float* __restrict__ dinv,
    const float* __restrict__ bias, float* __restrict__ Y) {
  const int wave = threadIdx.x >> 6;
  const int lane = threadIdx.x & 63;
  const int n = blockIdx.x * 4 + wave;
  if (n >= N_NODES) return;
  const float dn = dinv[n];
  const float selfw = dn * dn;
  const int beg = rowptr[n], end = rowptr[n + 1];
  const int jal = min((beg + 3) & ~3, end);      // align to 16B for int4
  const int jend = jal + ((end - jal) & ~7);     // 8-wise main loop end
  const int jend4 = jend + ((end - jend) & ~3);  // 4-wise cleanup end

  if constexpr (OC == 128) {
    const __half2* H2 = (const __half2*)H;
    float2 hv = __half22float2(H2[(size_t)n * 64 + lane]);
    float ax = hv.x * selfw, ay = hv.y * selfw;
    for (int j = beg; j < jal; ++j) {
      int s = eSrc[j];
      float w = dinv[s] * dn;
      float2 v = __half22float2(H2[(size_t)s * 64 + lane]);
      ax = fmaf(v.x, w, ax);
      ay = fmaf(v.y, w, ay);
    }
    for (int j = jal; j < jend; j += 8) {
      int4 s0 = *(const int4*)(eSrc + j);
      int4 s1 = *(const int4*)(eSrc + j + 4);
      __half2 h0 = H2[(size_t)s0.x * 64 + lane];
      __half2 h1 = H2[(size_t)s0.y * 64 + lane];
      __half2 h2 = H2[(size_t)s0.z * 64 + lane];
      __half2 h3 = H2[(size_t)s0.w * 64 + lane];
      __half2 h4 = H2[(size_t)s1.x * 64 + lane];
      __half2 h5 = H2[(size_t)s1.y * 64 + lane];
      __half2 h6 = H2[(size_t)s1.z * 64 + lane];
      __half2 h7 = H2[(size_t)s1.w * 64 + lane];
      float w0 = dinv[s0.x] * dn;
      float w1 = dinv[s0.y] * dn;
      float w2 = dinv[s0.z] * dn;
      float w3 = dinv[s0.w] * dn;
      float w4 = dinv[s1.x] * dn;
      float w5 = dinv[s1.y] * dn;
      float w6 = dinv[s1.z] * dn;
      float w7 = dinv[s1.w] * dn;
      float2 v0 = __half22float2(h0);
      float2 v1 = __half22float2(h1);
      float2 v2 = __half22float2(h2);
      float2 v3 = __half22float2(h3);
      float2 v4 = __half22float2(h4);
      float2 v5 = __half22float2(h5);
      float2 v6 = __half22float2(h6);
      float2 v7 = __half22float2(h7);
      ax = fmaf(v0.x, w0, ax); ay = fmaf(v0.y, w0, ay);
      ax = fmaf(v1.x, w1, ax); ay = fmaf(v1.y, w1, ay);
      ax = fmaf(v2.x, w2, ax); ay = fmaf(v2.y, w2, ay);
      ax = fmaf(v3.x, w3, ax); ay = fmaf(v3.y, w3, ay);
      ax = fmaf(v4.x, w4, ax); ay = fmaf(v4.y, w4, ay);
      ax = fmaf(v5.x, w5, ax); ay = fmaf(v5.y, w5, ay);
      ax = fmaf(v6.x, w6, ax); ay = fmaf(v6.y, w6, ay);
      ax = fmaf(v7.x, w7, ax); ay = fmaf(v7.y, w7, ay);
    }
    for (int j = jend; j < jend4; j += 4) {
      int4 s = *(const int4*)(eSrc + j);
      __half2 h0 = H2[(size_t)s.x * 64 + lane];
      __half2 h1 = H2[(size_t)s.y * 64 + lane];
      __half2 h2 = H2[(size_t)s.z * 64 + lane];
      __half2 h3 = H2[(size_t)s.w * 64 + lane];
      float w0 = dinv[s.x] * dn;
      float w1 = dinv[s.y] * dn;
      float w2 = dinv[s.z] * dn;
      float w3 = dinv[s.w] * dn;
      float2 v0 = __half22float2(h0);
      float2 v1 = __half22float2(h1);
      float2 v2 = __half22float2(h2);
      float2 v3 = __half22float2(h3);
      ax = fmaf(v0.x, w0, ax); ay = fmaf(v0.y, w0, ay);
      ax = fmaf(v1.x, w1, ax); ay = fmaf(v1.y, w1, ay);
      ax = fmaf(v2.x, w2, ax); ay = fmaf(v2.y, w2, ay);
      ax = fmaf(v3.x, w3, ax); ay = fmaf(v3.y, w3, ay);
    }
    for (int j = jend4; j < end; ++j) {
      int s = eSrc[j];
      float w = dinv[s] * dn;
      float2 v = __half22float2(H2[(size_t)s * 64 + lane]);
      ax = fmaf(v.x, w, ax);
      ay = fmaf(v.y, w, ay);
    }
    float2 bb = ((const float2*)bias)[lane];
    float2 o;
    o.x = fmaxf(ax + bb.x, 0.f);
    o.y = fmaxf(ay + bb.y, 0.f);
    ((float2*)Y)[(size_t)n * 64 + lane] = o;
  } else {
    float a = __half2float(H[(size_t)n * 64 + lane]) * selfw;
    for (int j = beg; j < jal; ++j) {
      int s = eSrc[j];
      a = fmaf(__half2float(H[(size_t)s * 64 + lane]), dinv[s] * dn, a);
    }
    for (int j = jal; j < jend; j += 8) {
      int4 s0 = *(const int4*)(eSrc + j);
      int4 s1 = *(const int4*)(eSrc + j + 4);
      __half h0 = H[(size_t)s0.x * 64 + lane];
      __half h1 = H[(size_t)s0.y * 64 + lane];
      __half h2 = H[(size_t)s0.z * 64 + lane];
      __half h3 = H[(size_t)s0.w * 64 + lane];
      __half h4 = H[(size_t)s1.x * 64 + lane];
      __half h5 = H[(size_t)s1.y * 64 + lane];
      __half h6 = H[(size_t)s1.z * 64 + lane];
      __half h7 = H[(size_t)s1.w * 64 + lane];
      float w0 = dinv[s0.x] * dn;
      float w1 = dinv[s0.y] * dn;
      float w2 = dinv[s0.z] * dn;
      float w3 = dinv[s0.w] * dn;
      float w4 = dinv[s1.x] * dn;
      float w5 = dinv[s1.y] * dn;
      float w6 = dinv[s1.z] * dn;
      float w7 = dinv[s1.w] * dn;
      a = fmaf(__half2float(h0), w0, a);
      a = fmaf(__half2float(h1), w1, a);
      a = fmaf(__half2float(h2), w2, a);
      a = fmaf(__half2float(h3), w3, a);
      a = fmaf(__half2float(h4), w4, a);
      a = fmaf(__half2float(h5), w5, a);
      a = fmaf(__half2float(h6), w6, a);
      a = fmaf(__half2float(h7), w7, a);
    }
    for (int j = jend; j < jend4; j += 4) {
      int4 s = *(const int4*)(eSrc + j);
      float w0 = dinv[s.x] * dn;
      float w1 = dinv[s.y] * dn;
      float w2 = dinv[s.z] * dn;
      float w3 = dinv[s.w] * dn;
      a = fmaf(__half2float(H[(size_t)s.x * 64 + lane]), w0, a);
      a = fmaf(__half2float(H[(size_t)s.y * 64 + lane]), w1, a);
      a = fmaf(__half2float(H[(size_t)s.z * 64 + lane]), w2, a);
      a = fmaf(__half2float(H[(size_t)s.w * 64 + lane]), w3, a);
    }
    for (int j = jend4; j < end; ++j) {
      int s = eSrc[j];
      a = fmaf(__half2float(H[(size_t)s * 64 + lane]), dinv[s] * dn, a);
    }
    Y[(size_t)n * 64 + lane] = fmaxf(a + bias[lane], 0.f);
  }
}

extern "C" void kernel_launch(void* const* d_in, const int* in_sizes, int n_in,
                              void* d_out, int out_size, void* d_ws,
                              size_t ws_size, hipStream_t stream) {
  const float* x = (const float*)d_in[0];
  const int* ei = (const int*)d_in[1];
  const float* W1 = (const float*)d_in[2];
  const float* b1 = (const float*)d_in[3];
  const float* W2 = (const float*)d_in[4];
  const float* b2 = (const float*)d_in[5];
  const float* W3 = (const float*)d_in[6];
  const float* b3 = (const float*)d_in[7];
  const int* src = ei;
  const int* dst = ei + E_EDGES;

  size_t off = 0;
  auto alloc = [&](size_t bytes) -> void* {
    void* p = (char*)d_ws + off;
    off += (bytes + 255) & ~(size_t)255;
    return p;
  };
  int* cnt = (int*)alloc((size_t)N_NODES * 4);
  int* rowptr = (int*)alloc((size_t)(N_NODES + 1) * 4);
  int* cursor = (int*)alloc((size_t)N_NODES * 4);
  float* dinv = (float*)alloc((size_t)N_NODES * 4);
  int* bsum = (int*)alloc((size_t)SCAN_B * 4);
  int* boff = (int*)alloc((size_t)SCAN_B * 4);
  int* eSrc = (int*)alloc((size_t)E_EDGES * 4);
  __half* h = (__half*)alloc((size_t)N_NODES * 128 * 2);
  float* A = (float*)alloc((size_t)N_NODES * 128 * 4);
  ushort* wp1h = (ushort*)alloc((size_t)128 * 128 * 2);
  ushort* wp1l = (ushort*)alloc((size_t)128 * 128 * 2);
  ushort* wp2h = (ushort*)alloc((size_t)128 * 128 * 2);
  ushort* wp2l = (ushort*)alloc((size_t)128 * 128 * 2);
  ushort* wp3h = (ushort*)alloc((size_t)128 * 64 * 2);
  ushort* wp3l = (ushort*)alloc((size_t)128 * 64 * 2);

  hipMemsetAsync(cnt, 0, (size_t)N_NODES * 4, stream);
  hipMemsetAsync(cursor, 0, (size_t)N_NODES * 4, stream);

  const int E4B = (E_EDGES / 4 + 255) / 256;  // 1563
  count_kernel<<<E4B, 256, 0, stream>>>(dst, cnt);
  scan_part_kernel<<<SCAN_B, 256, 0, stream>>>(cnt, bsum);
  scan_tops_kernel<<<1, 128, 0, stream>>>(bsum, boff, rowptr);
  scan_write_kernel<<<SCAN_B, 256, 0, stream>>>(cnt, boff, rowptr, dinv);
  scatter_kernel<<<E4B, 256, 0, stream>>>(src, dst, rowptr, cursor, eSrc);
  packw_kernel<128><<<8, 256, 0, stream>>>(W1, wp1h, wp1l);
  packw_kernel<128><<<8, 256, 0, stream>>>(W2, wp2h, wp2l);
  packw_kernel<64><<<4, 256, 0, stream>>>(W3, wp3h, wp3l);

  const int GB = (N_NODES + 63) / 64;  // 1563
  const int AB = (N_NODES + 3) / 4;    // 25000

  gemm_kernel<128><<<GB, 256, 0, stream>>>(x, wp1h, wp1l, h);
  agg_kernel<128><<<AB, 256, 0, stream>>>(h, rowptr, eSrc, dinv, b1, A);
  gemm_kernel<128><<<GB, 256, 0, stream>>>(A, wp2h, wp2l, h);
  agg_kernel<128><<<AB, 256, 0, stream>>>(h, rowptr, eSrc, dinv, b2, A);
  gemm_kernel<64><<<GB, 256, 0, stream>>>(A, wp3h, wp3l, h);
  agg_kernel<64><<<AB, 256, 0, stream>>>(h, rowptr, eSrc, dinv, b3,
                                         (float*)d_out);
}

// Round 8
// 379.960 us; speedup vs baseline: 1.3065x; 1.3065x over previous
//
#include <hip/hip_runtime.h>
#include <hip/hip_bf16.h>
#include <hip/hip_fp16.h>

// GCN 3-layer forward for MI355X (gfx950).
//   1. rank_kernel: r = atomicAdd(cnt[dst]), eRank[e] = r (coalesced store;
//      histogram is a byproduct -> no separate count pass)
//   2. 3-kernel multi-block exclusive scan -> CSR rowptr (+fused dinv)
//   3. place_kernel: pos = rowptr[dst] + eRank[e]; eSW[pos] = (src, w).
//      NO atomic, fire-and-forget store -> latency fully pipelined.
//   4. per layer: split-bf16 MFMA GEMM h=X@W (fp16 out), then wave-per-node
//      CSR gather-reduce over packed (src,w) edges (+bias, +self, ReLU).
// R4: GEMM on matrix cores via split-bf16 (3 MFMAs, ~2^-17 rel err).
// R5: H stored fp16 (agg was BW-pinned at ~3.9 TB/s with f32 H).
// R6: packed int2 (src,w) payload. XCD-grouping: no effect -> removed.
// R7 lessons: random-4B-store writeback is 64B/line STRUCTURAL (nt-stores
//     don't help); unrolling atomic-return chains cuts TLP and regresses;
//     on-the-fly dinv[s] in agg adds a dependent load -> keep packed w.
// R8: split rank/place as above; agg reverted to R6 form.

constexpr int N_NODES = 100000;
constexpr int E_EDGES = 1600000;
constexpr int SCAN_B = (N_NODES + 1023) / 1024;  // 98 blocks of 1024 elems

typedef short short8 __attribute__((ext_vector_type(8)));
typedef float f32x4 __attribute__((ext_vector_type(4)));

// Pass 1: one atomic per edge, rank stored coalesced.
__global__ __launch_bounds__(256) void rank_kernel(
    const int* __restrict__ dst, int* __restrict__ cnt,
    int* __restrict__ eRank) {
  int e = blockIdx.x * 256 + threadIdx.x;
  if (e < E_EDGES) eRank[e] = atomicAdd(&cnt[dst[e]], 1);
}

// --- 3-kernel scan: cnt[N] -> rowptr[N+1] (exclusive), dinv fused ---
__global__ __launch_bounds__(256) void scan_part_kernel(
    const int* __restrict__ cnt, int* __restrict__ bsum) {
  __shared__ int red[256];
  const int t = threadIdx.x;
  int base = blockIdx.x * 1024 + t * 4;
  int4 v = make_int4(0, 0, 0, 0);
  if (base < N_NODES) v = *(const int4*)(cnt + base);
  red[t] = v.x + v.y + v.z + v.w;
  __syncthreads();
  for (int off = 128; off > 0; off >>= 1) {
    if (t < off) red[t] += red[t + off];
    __syncthreads();
  }
  if (t == 0) bsum[blockIdx.x] = red[0];
}

__global__ __launch_bounds__(128) void scan_tops_kernel(
    const int* __restrict__ bsum, int* __restrict__ boff,
    int* __restrict__ rowptr) {
  __shared__ int part[128];
  const int t = threadIdx.x;
  int v = (t < SCAN_B) ? bsum[t] : 0;
  part[t] = v;
  __syncthreads();
  for (int off = 1; off < 128; off <<= 1) {
    int add = (t >= off) ? part[t - off] : 0;
    __syncthreads();
    part[t] += add;
    __syncthreads();
  }
  if (t < SCAN_B) boff[t] = part[t] - v;  // exclusive
  if (t == 127) rowptr[N_NODES] = part[127];
}

__global__ __launch_bounds__(256) void scan_write_kernel(
    const int* __restrict__ cnt, const int* __restrict__ boff,
    int* __restrict__ rowptr, float* __restrict__ dinv) {
  __shared__ int part[256];
  const int t = threadIdx.x;
  int base = blockIdx.x * 1024 + t * 4;
  int4 v = make_int4(0, 0, 0, 0);
  if (base < N_NODES) v = *(const int4*)(cnt + base);
  int s = v.x + v.y + v.z + v.w;
  part[t] = s;
  __syncthreads();
  for (int off = 1; off < 256; off <<= 1) {
    int add = (t >= off) ? part[t - off] : 0;
    __syncthreads();
    part[t] += add;
    __syncthreads();
  }
  if (base < N_NODES) {
    int run = boff[blockIdx.x] + part[t] - s;
    int4 o;
    o.x = run;
    o.y = run + v.x;
    o.z = run + v.x + v.y;
    o.w = run + v.x + v.y + v.z;
    *(int4*)(rowptr + base) = o;
    float4 dv;
    dv.x = rsqrtf((float)v.x + 1.0f);  // +1 self loop
    dv.y = rsqrtf((float)v.y + 1.0f);
    dv.z = rsqrtf((float)v.z + 1.0f);
    dv.w = rsqrtf((float)v.w + 1.0f);
    *(float4*)(dinv + base) = dv;
  }
}

// Pass 2: atomic-free placement. All loads independent, store needs no
// return -> the wave streams edges at full pipeline depth.
__global__ __launch_bounds__(256) void place_kernel(
    const int* __restrict__ src, const int* __restrict__ dst,
    const int* __restrict__ eRank, const int* __restrict__ rowptr,
    const float* __restrict__ dinv, int2* __restrict__ eSW) {
  int e = blockIdx.x * 256 + threadIdx.x;
  if (e < E_EDGES) {
    int d = dst[e];
    int s = src[e];
    int pos = rowptr[d] + eRank[e];
    eSW[pos] = make_int2(s, __float_as_int(dinv[s] * dinv[d]));
  }
}

// bf16 split helpers (manual RNE; inputs finite)
__device__ inline ushort bf_round(float x) {
  uint u = __float_as_uint(x);
  return (ushort)((u + 0x7FFFu + ((u >> 16) & 1u)) >> 16);
}
__device__ inline ushort bf_split(float x, float* rem) {
  ushort h = bf_round(x);
  *rem = x - __uint_as_float((uint)h << 16);
  return h;
}

// Pack W [128][OC] f32 into fragment-linear hi/lo bf16:
// chunk id = ((nt*4 + ks)*4 + g)*16 + col holds 8 bf16:
//   W[ks*32 + g*8 + j][nt*16 + col], j = 0..7.
template <int OC>
__global__ __launch_bounds__(256) void packw_kernel(
    const float* __restrict__ W, ushort* __restrict__ hi,
    ushort* __restrict__ lo) {
  int id = blockIdx.x * 256 + threadIdx.x;
  if (id >= OC * 16) return;  // (OC/16)*4*4*16 chunks
  int col = id & 15;
  int g = (id >> 4) & 3;
  int ks = (id >> 6) & 3;
  int nt = id >> 8;
  int k0 = ks * 32 + g * 8;
  int n = nt * 16 + col;
  ushort h8[8], l8[8];
#pragma unroll
  for (int j = 0; j < 8; ++j) {
    float rem;
    h8[j] = bf_split(W[(size_t)(k0 + j) * OC + n], &rem);
    l8[j] = bf_round(rem);
  }
  size_t base = (size_t)id * 8;
#pragma unroll
  for (int j = 0; j < 8; ++j) {
    hi[base + j] = h8[j];
    lo[base + j] = l8[j];
  }
}

// Split-bf16 MFMA GEMM: H[N, OC] = X[N, 128] @ W[128, OC], H in fp16.
// 4 waves/block, 16 rows/wave (M-tile 64). W (packed hi/lo) staged in LDS;
// A-fragments loaded direct from global (X is L2/L3-resident) and split
// to hi/lo in registers. 3 MFMAs per (nt, ks): hi*hi + hi*lo + lo*hi.
template <int OC>
__global__ __launch_bounds__(256) void gemm_kernel(
    const float* __restrict__ X, const ushort* __restrict__ Whi,
    const ushort* __restrict__ Wlo, __half* __restrict__ H) {
  constexpr int NT = OC / 16;
  __shared__ ushort sWhi[OC * 128];
  __shared__ ushort sWlo[OC * 128];
  const int t = threadIdx.x;
  {  // stage packed W (contiguous, coalesced uint4 copies)
    const uint4* gh = (const uint4*)Whi;
    const uint4* gl = (const uint4*)Wlo;
    uint4* sh = (uint4*)sWhi;
    uint4* sl = (uint4*)sWlo;
    for (int i = t; i < OC * 128 / 8; i += 256) {
      sh[i] = gh[i];
      sl[i] = gl[i];
    }
  }
  const int wid = t >> 6;
  const int lane = t & 63;
  const int row = blockIdx.x * 64 + wid * 16 + (lane & 15);
  const bool ok = row < N_NODES;
  const int g = lane >> 4;  // k-group 0..3

  // Load + split A fragments for all 4 k-steps
  short8 ahi[4], alo[4];
  const float* xr = X + (size_t)row * 128;
#pragma unroll
  for (int ks = 0; ks < 4; ++ks) {
    float f[8];
    if (ok) {
      float4 f0 = *(const float4*)(xr + ks * 32 + g * 8);
      float4 f1 = *(const float4*)(xr + ks * 32 + g * 8 + 4);
      f[0] = f0.x; f[1] = f0.y; f[2] = f0.z; f[3] = f0.w;
      f[4] = f1.x; f[5] = f1.y; f[6] = f1.z; f[7] = f1.w;
    } else {
#pragma unroll
      for (int j = 0; j < 8; ++j) f[j] = 0.f;
    }
    union { short8 v; ushort u[8]; } h, l;
#pragma unroll
    for (int j = 0; j < 8; ++j) {
      float rem;
      h.u[j] = bf_split(f[j], &rem);
      l.u[j] = bf_round(rem);
    }
    ahi[ks] = h.v;
    alo[ks] = l.v;
  }
  __syncthreads();

#pragma unroll
  for (int nt = 0; nt < NT; ++nt) {
    f32x4 acc = {0.f, 0.f, 0.f, 0.f};
#pragma unroll
    for (int ks = 0; ks < 4; ++ks) {
      int off = (((nt * 4 + ks) * 4 + g) * 16 + (lane & 15)) * 8;
      short8 bhi = *(const short8*)&sWhi[off];
      short8 blo = *(const short8*)&sWlo[off];
      acc = __builtin_amdgcn_mfma_f32_16x16x32_bf16(alo[ks], bhi, acc, 0, 0, 0);
      acc = __builtin_amdgcn_mfma_f32_16x16x32_bf16(ahi[ks], blo, acc, 0, 0, 0);
      acc = __builtin_amdgcn_mfma_f32_16x16x32_bf16(ahi[ks], bhi, acc, 0, 0, 0);
    }
    // C: col = lane&15, row_in_tile = (lane>>4)*4 + r
#pragma unroll
    for (int r = 0; r < 4; ++r) {
      int rr = blockIdx.x * 64 + wid * 16 + g * 4 + r;
      if (rr < N_NODES)
        H[(size_t)rr * OC + nt * 16 + (lane & 15)] = __float2half(acc[r]);
    }
  }
}

// Wave-per-node CSR aggregation over fp16 H table, packed (src,w) edges:
// Y[n] = relu(b + dinv[n]^2*H[n] + sum_e w_e * H[src_e]), Y in f32.
// Edge loop unrolled x8 (int4 loads of 2 packed edges each): eight
// independent H-row gathers in flight per wave.
template <int OC>
__global__ __launch_bounds__(256) void agg_kernel(
    const __half* __restrict__ H, const int* __restrict__ rowptr,
    const int2* __restrict__ eSW, const float* __restrict__ dinv,
    const float* __restrict__ bias, float* __restrict__ Y) {
  const int wave = threadIdx.x >> 6;
  const int lane = threadIdx.x & 63;
  const int n = blockIdx.x * 4 + wave;
  if (n >= N_NODES) return;
  const float dn = dinv[n];
  const float selfw = dn * dn;
  const int beg = rowptr[n], end = rowptr[n + 1];
  const int jal = min(beg + (beg & 1), end);     // align to 16B (even idx)
  const int jend = jal + ((end - jal) & ~7);     // 8-wise main loop end
  const int jend2 = jend + ((end - jend) & ~1);  // 2-wise cleanup end

  if constexpr (OC == 128) {
    const __half2* H2 = (const __half2*)H;
    float2 hv = __half22float2(H2[(size_t)n * 64 + lane]);
    float ax = hv.x * selfw, ay = hv.y * selfw;
    for (int j = beg; j < jal; ++j) {
      int2 p = eSW[j];
      float2 v = __half22float2(H2[(size_t)p.x * 64 + lane]);
      float w = __int_as_float(p.y);
      ax = fmaf(v.x, w, ax);
      ay = fmaf(v.y, w, ay);
    }
    for (int j = jal; j < jend; j += 8) {
      int4 p0 = *(const int4*)(eSW + j);      // s0 w0 s1 w1
      int4 p1 = *(const int4*)(eSW + j + 2);
      int4 p2 = *(const int4*)(eSW + j + 4);
      int4 p3 = *(const int4*)(eSW + j + 6);
      __half2 h0 = H2[(size_t)p0.x * 64 + lane];
      __half2 h1 = H2[(size_t)p0.z * 64 + lane];
      __half2 h2 = H2[(size_t)p1.x * 64 + lane];
      __half2 h3 = H2[(size_t)p1.z * 64 + lane];
      __half2 h4 = H2[(size_t)p2.x * 64 + lane];
      __half2 h5 = H2[(size_t)p2.z * 64 + lane];
      __half2 h6 = H2[(size_t)p3.x * 64 + lane];
      __half2 h7 = H2[(size_t)p3.z * 64 + lane];
      float2 v0 = __half22float2(h0);
      float2 v1 = __half22float2(h1);
      float2 v2 = __half22float2(h2);
      float2 v3 = __half22float2(h3);
      float2 v4 = __half22float2(h4);
      float2 v5 = __half22float2(h5);
      float2 v6 = __half22float2(h6);
      float2 v7 = __half22float2(h7);
      ax = fmaf(v0.x, __int_as_float(p0.y), ax);
      ay = fmaf(v0.y, __int_as_float(p0.y), ay);
      ax = fmaf(v1.x, __int_as_float(p0.w), ax);
      ay = fmaf(v1.y, __int_as_float(p0.w), ay);
      ax = fmaf(v2.x, __int_as_float(p1.y), ax);
      ay = fmaf(v2.y, __int_as_float(p1.y), ay);
      ax = fmaf(v3.x, __int_as_float(p1.w), ax);
      ay = fmaf(v3.y, __int_as_float(p1.w), ay);
      ax = fmaf(v4.x, __int_as_float(p2.y), ax);
      ay = fmaf(v4.y, __int_as_float(p2.y), ay);
      ax = fmaf(v5.x, __int_as_float(p2.w), ax);
      ay = fmaf(v5.y, __int_as_float(p2.w), ay);
      ax = fmaf(v6.x, __int_as_float(p3.y), ax);
      ay = fmaf(v6.y, __int_as_float(p3.y), ay);
      ax = fmaf(v7.x, __int_as_float(p3.w), ax);
      ay = fmaf(v7.y, __int_as_float(p3.w), ay);
    }
    for (int j = jend; j < jend2; j += 2) {
      int4 p = *(const int4*)(eSW + j);
      float2 v0 = __half22float2(H2[(size_t)p.x * 64 + lane]);
      float2 v1 = __half22float2(H2[(size_t)p.z * 64 + lane]);
      ax = fmaf(v0.x, __int_as_float(p.y), ax);
      ay = fmaf(v0.y, __int_as_float(p.y), ay);
      ax = fmaf(v1.x, __int_as_float(p.w), ax);
      ay = fmaf(v1.y, __int_as_float(p.w), ay);
    }
    for (int j = jend2; j < end; ++j) {
      int2 p = eSW[j];
      float2 v = __half22float2(H2[(size_t)p.x * 64 + lane]);
      float w = __int_as_float(p.y);
      ax = fmaf(v.x, w, ax);
      ay = fmaf(v.y, w, ay);
    }
    float2 bb = ((const float2*)bias)[lane];
    float2 o;
    o.x = fmaxf(ax + bb.x, 0.f);
    o.y = fmaxf(ay + bb.y, 0.f);
    ((float2*)Y)[(size_t)n * 64 + lane] = o;
  } else {
    float a = __half2float(H[(size_t)n * 64 + lane]) * selfw;
    for (int j = beg; j < jal; ++j) {
      int2 p = eSW[j];
      a = fmaf(__half2float(H[(size_t)p.x * 64 + lane]),
               __int_as_float(p.y), a);
    }
    for (int j = jal; j < jend; j += 8) {
      int4 p0 = *(const int4*)(eSW + j);
      int4 p1 = *(const int4*)(eSW + j + 2);
      int4 p2 = *(const int4*)(eSW + j + 4);
      int4 p3 = *(const int4*)(eSW + j + 6);
      __half h0 = H[(size_t)p0.x * 64 + lane];
      __half h1 = H[(size_t)p0.z * 64 + lane];
      __half h2 = H[(size_t)p1.x * 64 + lane];
      __half h3 = H[(size_t)p1.z * 64 + lane];
      __half h4 = H[(size_t)p2.x * 64 + lane];
      __half h5 = H[(size_t)p2.z * 64 + lane];
      __half h6 = H[(size_t)p3.x * 64 + lane];
      __half h7 = H[(size_t)p3.z * 64 + lane];
      a = fmaf(__half2float(h0), __int_as_float(p0.y), a);
      a = fmaf(__half2float(h1), __int_as_float(p0.w), a);
      a = fmaf(__half2float(h2), __int_as_float(p1.y), a);
      a = fmaf(__half2float(h3), __int_as_float(p1.w), a);
      a = fmaf(__half2float(h4), __int_as_float(p2.y), a);
      a = fmaf(__half2float(h5), __int_as_float(p2.w), a);
      a = fmaf(__half2float(h6), __int_as_float(p3.y), a);
      a = fmaf(__half2float(h7), __int_as_float(p3.w), a);
    }
    for (int j = jend; j < jend2; j += 2) {
      int4 p = *(const int4*)(eSW + j);
      a = fmaf(__half2float(H[(size_t)p.x * 64 + lane]),
               __int_as_float(p.y), a);
      a = fmaf(__half2float(H[(size_t)p.z * 64 + lane]),
               __int_as_float(p.w), a);
    }
    for (int j = jend2; j < end; ++j) {
      int2 p = eSW[j];
      a = fmaf(__half2float(H[(size_t)p.x * 64 + lane]),
               __int_as_float(p.y), a);
    }
    Y[(size_t)n * 64 + lane] = fmaxf(a + bias[lane], 0.f);
  }
}

extern "C" void kernel_launch(void* const* d_in, const int* in_sizes, int n_in,
                              void* d_out, int out_size, void* d_ws,
                              size_t ws_size, hipStream_t stream) {
  const float* x = (const float*)d_in[0];
  const int* ei = (const int*)d_in[1];
  const float* W1 = (const float*)d_in[2];
  const float* b1 = (const float*)d_in[3];
  const float* W2 = (const float*)d_in[4];
  const float* b2 = (const float*)d_in[5];
  const float* W3 = (const float*)d_in[6];
  const float* b3 = (const float*)d_in[7];
  const int* src = ei;
  const int* dst = ei + E_EDGES;

  size_t off = 0;
  auto alloc = [&](size_t bytes) -> void* {
    void* p = (char*)d_ws + off;
    off += (bytes + 255) & ~(size_t)255;
    return p;
  };
  int* cnt = (int*)alloc((size_t)N_NODES * 4);
  int* rowptr = (int*)alloc((size_t)(N_NODES + 1) * 4);
  float* dinv = (float*)alloc((size_t)N_NODES * 4);
  int* bsum = (int*)alloc((size_t)SCAN_B * 4);
  int* boff = (int*)alloc((size_t)SCAN_B * 4);
  int* eRank = (int*)alloc((size_t)E_EDGES * 4);
  int2* eSW = (int2*)alloc((size_t)E_EDGES * 8);
  __half* h = (__half*)alloc((size_t)N_NODES * 128 * 2);
  float* A = (float*)alloc((size_t)N_NODES * 128 * 4);
  ushort* wp1h = (ushort*)alloc((size_t)128 * 128 * 2);
  ushort* wp1l = (ushort*)alloc((size_t)128 * 128 * 2);
  ushort* wp2h = (ushort*)alloc((size_t)128 * 128 * 2);
  ushort* wp2l = (ushort*)alloc((size_t)128 * 128 * 2);
  ushort* wp3h = (ushort*)alloc((size_t)128 * 64 * 2);
  ushort* wp3l = (ushort*)alloc((size_t)128 * 64 * 2);

  hipMemsetAsync(cnt, 0, (size_t)N_NODES * 4, stream);

  const int EB = (E_EDGES + 255) / 256;  // 6250
  rank_kernel<<<EB, 256, 0, stream>>>(dst, cnt, eRank);
  scan_part_kernel<<<SCAN_B, 256, 0, stream>>>(cnt, bsum);
  scan_tops_kernel<<<1, 128, 0, stream>>>(bsum, boff, rowptr);
  scan_write_kernel<<<SCAN_B, 256, 0, stream>>>(cnt, boff, rowptr, dinv);
  place_kernel<<<EB, 256, 0, stream>>>(src, dst, eRank, rowptr, dinv, eSW);
  packw_kernel<128><<<8, 256, 0, stream>>>(W1, wp1h, wp1l);
  packw_kernel<128><<<8, 256, 0, stream>>>(W2, wp2h, wp2l);
  packw_kernel<64><<<4, 256, 0, stream>>>(W3, wp3h, wp3l);

  const int GB = (N_NODES + 63) / 64;  // 1563
  const int AB = (N_NODES + 3) / 4;    // 25000

  gemm_kernel<128><<<GB, 256, 0, stream>>>(x, wp1h, wp1l, h);
  agg_kernel<128><<<AB, 256, 0, stream>>>(h, rowptr, eSW, dinv, b1, A);
  gemm_kernel<128><<<GB, 256, 0, stream>>>(A, wp2h, wp2l, h);
  agg_kernel<128><<<AB, 256, 0, stream>>>(h, rowptr, eSW, dinv, b2, A);
  gemm_kernel<64><<<GB, 256, 0, stream>>>(A, wp3h, wp3l, h);
  agg_kernel<64><<<AB, 256, 0, stream>>>(h, rowptr, eSW, dinv, b3,
                                         (float*)d_out);
}